// Round 7
// baseline (117.567 us; speedup 1.0000x reference)
//
#include <hip/hip_runtime.h>
#include <hip/hip_bf16.h>

typedef short bf16x8 __attribute__((ext_vector_type(8)));
typedef short bf16x4 __attribute__((ext_vector_type(4)));
typedef float f32x4  __attribute__((ext_vector_type(4)));

#define NI 256
#define NJ 256
#define NC 128
#define NH 4
#define ND 32

// ---- workspace layout (bytes) ----
#define WB_OFF    0           // wqkv bf16 [384][128] (row = op*128 + h*32 + d), UNpermuted
#define WO_BF_OFF 98304       // wo bf16 [128][128], columns sigma-permuted per 32-chunk
#define XN_OFF    131072      // xn bf16 [65536 tok][128]
#define TBM_OFF   16908288    // [256 i][4 h][256 j] f32 (tb + mask bias)

// k-slot permutation of the D->B-fragment bitcast:
//   pack j<4 <- tile_lo reg j (value index g*4+j), j>=4 <- tile_hi reg j-4 (16+g*4+j-4)
//   => slot p = g*8+j holds value index pi(g,j).  sigma = pi^-1:
//   sigma(t) = ((t&15)>>2)*8 + (t&3) + (t>>4)*4   (t in [0,32))

__device__ __forceinline__ short f2bf(float f) {
    return __builtin_bit_cast(short, __float2bfloat16(f));
}
__device__ __forceinline__ bf16x8 pack8(f32x4 lo, f32x4 hi) {
    bf16x8 u;
    #pragma unroll
    for (int j = 0; j < 4; ++j) { u[j] = f2bf(lo[j]); u[4 + j] = f2bf(hi[j]); }
    return u;
}

// ================= k_pre: LN + tb + mask bias (blocks 0..1023); weight prep (1024..1055) =================
__global__ __launch_bounds__(256, 8)
void k_pre(const float* __restrict__ x, const float* __restrict__ mask,
           const float* __restrict__ ln_g, const float* __restrict__ ln_b,
           const float* __restrict__ wb, const float* __restrict__ wq,
           const float* __restrict__ wk, const float* __restrict__ wv,
           const float* __restrict__ wo, char* __restrict__ ws)
{
    const int bid = blockIdx.x;
    const int tid = threadIdx.x;

    if (bid >= 1024) {   // ---- weight prep ----
        const int base = ((bid - 1024) * 256 + tid) * 8;
        if (base < 49152) {          // wqkv: linear bf16
            const int t = base >> 14;
            const float* src = (t == 0 ? wq : (t == 1 ? wk : wv)) + (base & 16383);
            short* dst = (short*)(ws + WB_OFF) + base;
            #pragma unroll
            for (int u = 0; u < 2; ++u) {
                f32x4 v = *(const f32x4*)(src + 4 * u);
                bf16x4 o;
                #pragma unroll
                for (int r = 0; r < 4; ++r) o[r] = f2bf(v[r]);
                *(bf16x4*)(dst + 4 * u) = o;
            }
        } else {                      // wo: sigma-permuted columns
            const int idx = base - 49152;
            const int c = idx >> 7;
            const int dbase = idx & 127;
            short* dst = (short*)(ws + WO_BF_OFF) + (size_t)c * NC;
            #pragma unroll
            for (int u = 0; u < 8; ++u) {
                const int d = dbase + u;
                const int t = d & 31;
                const int p = ((t & 15) >> 2) * 8 + (t & 3) + ((t >> 4) << 2);
                dst[((d >> 5) << 5) + p] = f2bf(wo[(size_t)c * NC + d]);
            }
        }
        return;
    }

    // ---- LN: lane-linear loads; lanes 0-31 = token 2k, 32-63 = token 2k+1 ----
    const int lane = tid & 63;
    const int wv_  = tid >> 6;
    const int l5   = lane & 31;
    const int half = lane >> 5;
    const int c0   = l5 * 4;

    f32x4 gv = *(const f32x4*)(ln_g + c0);
    f32x4 bv = *(const f32x4*)(ln_b + c0);
    f32x4 gwv[4];
    float Gh[4], Bh[4];
    #pragma unroll
    for (int h = 0; h < 4; ++h) {
        f32x4 w = *(const f32x4*)(wb + h * NC + c0);
        #pragma unroll
        for (int e = 0; e < 4; ++e) gwv[h][e] = gv[e] * w[e];
        Gh[h] = (gwv[h][0] + gwv[h][1]) + (gwv[h][2] + gwv[h][3]);
        Bh[h] = (bv[0] * w[0] + bv[1] * w[1]) + (bv[2] * w[2] + bv[3] * w[3]);
    }
    #pragma unroll
    for (int dd = 1; dd < 32; dd <<= 1) {
        #pragma unroll
        for (int h = 0; h < 4; ++h) {
            Gh[h] += __shfl_xor(Gh[h], dd);
            Bh[h] += __shfl_xor(Bh[h], dd);
        }
    }

    short* xnb = (short*)(ws + XN_OFF);
    float* tbm = (float*)(ws + TBM_OFF);
    const int t0 = bid * 64 + wv_ * 16;

    #pragma unroll
    for (int it = 0; it < 2; ++it) {
        const int tb8 = t0 + it * 8;
        const float* bp = x + (size_t)tb8 * NC;
        #pragma unroll
        for (int k = 0; k < 4; ++k) {
            f32x4 v = *(const f32x4*)(bp + k * 256 + lane * 4);   // lane-linear 16B
            const int tk = tb8 + k * 2 + half;
            float s  = v[0] + v[1] + v[2] + v[3];
            float s2 = v[0]*v[0] + v[1]*v[1] + v[2]*v[2] + v[3]*v[3];
            float d0 = v[0]*gwv[0][0] + v[1]*gwv[0][1] + v[2]*gwv[0][2] + v[3]*gwv[0][3];
            float d1 = v[0]*gwv[1][0] + v[1]*gwv[1][1] + v[2]*gwv[1][2] + v[3]*gwv[1][3];
            float d2 = v[0]*gwv[2][0] + v[1]*gwv[2][1] + v[2]*gwv[2][2] + v[3]*gwv[2][3];
            float d3 = v[0]*gwv[3][0] + v[1]*gwv[3][1] + v[2]*gwv[3][2] + v[3]*gwv[3][3];
            #pragma unroll
            for (int dd = 1; dd < 32; dd <<= 1) {
                s  += __shfl_xor(s, dd);
                s2 += __shfl_xor(s2, dd);
                d0 += __shfl_xor(d0, dd);
                d1 += __shfl_xor(d1, dd);
                d2 += __shfl_xor(d2, dd);
                d3 += __shfl_xor(d3, dd);
            }
            const float mu  = s * 0.0078125f;
            const float var = s2 * 0.0078125f - mu * mu;
            const float rs  = rsqrtf(var + 1e-5f);
            bf16x4 o;
            #pragma unroll
            for (int e = 0; e < 4; ++e) o[e] = f2bf((v[e] - mu) * rs * gv[e] + bv[e]);
            *(bf16x4*)(xnb + (size_t)tk * NC + c0) = o;
            if (l5 == 0) {
                const float mb = 1.0e9f * (mask[tk] - 1.0f);
                const int ii = tk >> 8, jj = tk & 255;
                const float d4[4] = {d0, d1, d2, d3};
                #pragma unroll
                for (int h = 0; h < 4; ++h)
                    tbm[(size_t)(ii * NH + h) * NJ + jj] = rs * (d4[h] - mu * Gh[h]) + Bh[h] + mb;
            }
        }
    }
}

// ================= k_fat3: per-row-i fused QKV + attention + out-projection =================
// 1024 thr (16 waves x 16 q); K/V double-buffered LDS (74.75KB); Q/P/O never touch LDS.
#define BUFSTRIDE 37376
#define SMEM_FAT  74752
__global__ __launch_bounds__(1024, 4)
void k_fat3(const char* __restrict__ ws, const float* __restrict__ wo_b,
            float* __restrict__ out)
{
    extern __shared__ __align__(16) char smem[];
    const int tid  = threadIdx.x;
    const int lane = tid & 63;
    const int wid  = tid >> 6;          // 0..15
    const int g    = lane >> 4;
    const int l16  = lane & 15;
    const int i    = blockIdx.x;        // grid 256
    const int tq   = wid * 16;

    const short* xn   = (const short*)(ws + XN_OFF) + (size_t)i * NJ * NC;
    const short* wqkv = (const short*)(ws + WB_OFF);
    const short* wop  = (const short*)(ws + WO_BF_OFF);
    const float* tbm  = (const float*)(ws + TBM_OFF) + (size_t)i * NH * NJ;

    const f32x4 z4 = {0.f, 0.f, 0.f, 0.f};
    const float SCALE = 0.17677669529663687f;  // 1/sqrt(32)

    bf16x8 qfA, qfB;
    bf16x8 ofrag[4];

    // PROJ head h into buffer b: K cols sigma(d), V^T cols sigma(token); q swapped -> B-frag
    auto PROJ = [&](int h, int b, bf16x8& qfo) {
        short (*kb)[40]  = (short(*)[40]) (smem + b * BUFSTRIDE);
        short (*vb)[264] = (short(*)[264])(smem + b * BUFSTRIDE + 20480);
        bf16x8 af[4];
        #pragma unroll
        for (int ks = 0; ks < 4; ++ks)
            af[ks] = *(const bf16x8*)(xn + (size_t)(tq + l16) * NC + ks * 32 + g * 8);
        // q (swapped): D[d][tok] -> pack to B-frag (k-slots = d in pi order)
        f32x4 a0 = z4, a1 = z4;
        #pragma unroll
        for (int ks = 0; ks < 4; ++ks) {
            bf16x8 w0 = *(const bf16x8*)(wqkv + (size_t)(h * ND + l16) * NC + ks * 32 + g * 8);
            bf16x8 w1 = *(const bf16x8*)(wqkv + (size_t)(h * ND + 16 + l16) * NC + ks * 32 + g * 8);
            a0 = __builtin_amdgcn_mfma_f32_16x16x32_bf16(w0, af[ks], a0, 0, 0, 0);
            a1 = __builtin_amdgcn_mfma_f32_16x16x32_bf16(w1, af[ks], a1, 0, 0, 0);
        }
        qfo = pack8(a0, a1);
        // k: D[tok][d] -> kb[tok][sigma(d)]
        #pragma unroll
        for (int sub = 0; sub < 2; ++sub) {
            f32x4 acc = z4;
            #pragma unroll
            for (int ks = 0; ks < 4; ++ks) {
                bf16x8 w = *(const bf16x8*)(wqkv + (size_t)(NC + h * ND + sub * 16 + l16) * NC + ks * 32 + g * 8);
                acc = __builtin_amdgcn_mfma_f32_16x16x32_bf16(af[ks], w, acc, 0, 0, 0);
            }
            const int col = ((l16 >> 2) << 3) + (l16 & 3) + (sub << 2);   // sigma(sub*16+l16)
            #pragma unroll
            for (int r = 0; r < 4; ++r)
                kb[tq + g * 4 + r][col] = f2bf(acc[r]);
        }
        // v: D[tok][d] -> vb[d][chunk*32 + sigma(tok&31)]
        #pragma unroll
        for (int sub = 0; sub < 2; ++sub) {
            f32x4 acc = z4;
            #pragma unroll
            for (int ks = 0; ks < 4; ++ks) {
                bf16x8 w = *(const bf16x8*)(wqkv + (size_t)(2 * NC + h * ND + sub * 16 + l16) * NC + ks * 32 + g * 8);
                acc = __builtin_amdgcn_mfma_f32_16x16x32_bf16(af[ks], w, acc, 0, 0, 0);
            }
            bf16x4 pk;
            #pragma unroll
            for (int r = 0; r < 4; ++r) pk[r] = f2bf(acc[r]);
            *(bf16x4*)(&vb[sub * 16 + l16][((tq >> 5) << 5) + (g << 3) + (((tq >> 4) & 1) << 2)]) = pk;
        }
    };

    PROJ(0, 0, qfA);
    __syncthreads();

    #pragma unroll
    for (int h = 0; h < 4; ++h) {
        if (h < 3) PROJ(h + 1, (h + 1) & 1, qfB);   // prefetch next head's K/V/q

        const short (*kb)[40]  = (const short(*)[40]) (smem + (h & 1) * BUFSTRIDE);
        const short (*vb)[264] = (const short(*)[264])(smem + (h & 1) * BUFSTRIDE + 20480);
        const float tbq = tbm[h * NJ + tq + l16];   // lane's own query bias (tb + mask)

        // QK^T swapped: s[kt] rows=k, col=q=l16 (lane owns one q)
        f32x4 s[16];
        #pragma unroll
        for (int kt = 0; kt < 16; ++kt) {
            bf16x8 kf = *(const bf16x8*)(&kb[kt * 16 + l16][g * 8]);
            s[kt] = __builtin_amdgcn_mfma_f32_16x16x32_bf16(kf, qfA, z4, 0, 0, 0);
        }
        #pragma unroll
        for (int kt = 0; kt < 16; ++kt)
            #pragma unroll
            for (int r = 0; r < 4; ++r)
                s[kt][r] = fmaf(s[kt][r], SCALE, tbq);  // fp32: masked rows collapse exactly

        // max: in-lane tree (depth ~6) + 2 shfls
        float mk[16];
        #pragma unroll
        for (int kt = 0; kt < 16; ++kt)
            mk[kt] = fmaxf(fmaxf(s[kt][0], s[kt][1]), fmaxf(s[kt][2], s[kt][3]));
        #pragma unroll
        for (int st = 8; st >= 1; st >>= 1)
            #pragma unroll
            for (int k2 = 0; k2 < st; ++k2) mk[k2] = fmaxf(mk[k2], mk[k2 + st]);
        float m = mk[0];
        m = fmaxf(m, __shfl_xor(m, 16));
        m = fmaxf(m, __shfl_xor(m, 32));

        // exp + sum tree
        float sk[16];
        #pragma unroll
        for (int kt = 0; kt < 16; ++kt) {
            #pragma unroll
            for (int r = 0; r < 4; ++r) s[kt][r] = __expf(s[kt][r] - m);
            sk[kt] = (s[kt][0] + s[kt][1]) + (s[kt][2] + s[kt][3]);
        }
        #pragma unroll
        for (int st = 8; st >= 1; st >>= 1)
            #pragma unroll
            for (int k2 = 0; k2 < st; ++k2) sk[k2] += sk[k2 + st];
        float sum = sk[0];
        sum += __shfl_xor(sum, 16);
        sum += __shfl_xor(sum, 32);
        const float inv = 1.0f / sum;

        // PV: P bit-cast to B-frag in-register; V^T A-frag from sigma-permuted LDS
        f32x4 o0 = z4, o1 = z4;
        #pragma unroll
        for (int c = 0; c < 8; ++c) {
            bf16x8 pa = pack8(s[2 * c], s[2 * c + 1]);
            bf16x8 v0 = *(const bf16x8*)(&vb[l16][c * 32 + g * 8]);
            bf16x8 v1 = *(const bf16x8*)(&vb[16 + l16][c * 32 + g * 8]);
            o0 = __builtin_amdgcn_mfma_f32_16x16x32_bf16(v0, pa, o0, 0, 0, 0);
            o1 = __builtin_amdgcn_mfma_f32_16x16x32_bf16(v1, pa, o1, 0, 0, 0);
        }
        f32x4 on0, on1;   // deferred softmax normalization
        #pragma unroll
        for (int r = 0; r < 4; ++r) { on0[r] = o0[r] * inv; on1[r] = o1[r] * inv; }
        ofrag[h] = pack8(on0, on1);   // O^T -> B-frag (k-slots = d in pi order)

        if (h < 3) qfA = qfB;
        __syncthreads();
    }

    // ---- fused out-projection: out^T[c][q] = wo_perm . O^T  (all-register) ----
    #pragma unroll
    for (int ct = 0; ct < 8; ++ct) {
        f32x4 acc = z4;
        #pragma unroll
        for (int hh = 0; hh < 4; ++hh) {
            bf16x8 wa = *(const bf16x8*)(wop + (size_t)(ct * 16 + l16) * NC + hh * 32 + g * 8);
            acc = __builtin_amdgcn_mfma_f32_16x16x32_bf16(wa, ofrag[hh], acc, 0, 0, 0);
        }
        f32x4 bias = *(const f32x4*)(wo_b + ct * 16 + g * 4);
        #pragma unroll
        for (int r = 0; r < 4; ++r) acc[r] += bias[r];
        *(f32x4*)(out + ((size_t)i * NJ + tq + l16) * NC + ct * 16 + g * 4) = acc;
    }
}

extern "C" void kernel_launch(void* const* d_in, const int* in_sizes, int n_in,
                              void* d_out, int out_size, void* d_ws, size_t ws_size,
                              hipStream_t stream) {
    const float* x    = (const float*)d_in[0];
    const float* mask = (const float*)d_in[1];
    const float* ln_g = (const float*)d_in[2];
    const float* ln_b = (const float*)d_in[3];
    const float* wq   = (const float*)d_in[4];
    const float* wk   = (const float*)d_in[5];
    const float* wv   = (const float*)d_in[6];
    const float* wb   = (const float*)d_in[7];
    const float* wo   = (const float*)d_in[8];
    const float* wo_b = (const float*)d_in[9];
    float* out = (float*)d_out;
    char* ws   = (char*)d_ws;

    (void)hipFuncSetAttribute((const void*)k_fat3,
                              hipFuncAttributeMaxDynamicSharedMemorySize, SMEM_FAT);

    k_pre <<<dim3(1056), dim3(256),  0,        stream>>>(x, mask, ln_g, ln_b, wb, wq, wk, wv, wo, ws);
    k_fat3<<<dim3(NI),   dim3(1024), SMEM_FAT, stream>>>(ws, wo_b, out);
}